// Round 3
// baseline (323.288 us; speedup 1.0000x reference)
//
#include <hip/hip_runtime.h>

typedef _Float16 f16;
typedef f16  f16x4 __attribute__((ext_vector_type(4)));
typedef f16  f16x8 __attribute__((ext_vector_type(8)));
typedef float f32x4 __attribute__((ext_vector_type(4)));

#define B_  64
#define S_  2048
#define H_  512
#define K_  1024   // 2H

__device__ __forceinline__ float fast_tanh(float x){
  float ax = fabsf(x);
  float t  = __expf(-2.0f*ax);
  float r  = (1.0f - t) / (1.0f + t);
  return x < 0.0f ? -r : r;
}

// ---- k0a: repack We [1024][512] f32 -> Bg [(k>>3)][col][k&7] f16 ----
__global__ __launch_bounds__(256) void convert_we_k(const float* __restrict__ We,
                                                    f16* __restrict__ Bg){
  int idx = blockIdx.x*256 + threadIdx.x;      // 0..524287
  int k = idx >> 9, col = idx & 511;
  Bg[((k>>3)<<12) + (col<<3) + (k&7)] = (f16)We[idx];
}

// ---- k0b: dec_proj[b][col] = sum_k dh[b][k]*Wd[k][col] ----
__global__ __launch_bounds__(128) void decproj_k(const float* __restrict__ dh,
                                                 const float* __restrict__ Wd,
                                                 float* __restrict__ dp){
  __shared__ float s_dh[512];
  int b = blockIdx.x >> 2, cg = blockIdx.x & 3;
  int col = (cg<<7) + threadIdx.x;
  for (int i = threadIdx.x; i < 512; i += 128) s_dh[i] = dh[(b<<9) + i];
  __syncthreads();
  float a0=0.f,a1=0.f,a2=0.f,a3=0.f;
  for (int k = 0; k < 512; k += 4){
    a0 += s_dh[k+0]*Wd[(k+0)*512 + col];
    a1 += s_dh[k+1]*Wd[(k+1)*512 + col];
    a2 += s_dh[k+2]*Wd[(k+2)*512 + col];
    a3 += s_dh[k+3]*Wd[(k+3)*512 + col];
  }
  dp[(b<<9) + col] = (a0+a1)+(a2+a3);
}

// ---- k1: fused scores = v . tanh(dec_proj + enc@We) ----
// grid 2048 (= 64 b x 32 s-tiles), 512 threads (8 waves), tile 64x512, BK=32
__global__ __launch_bounds__(512, 4) void scores_k(
    const float* __restrict__ enc,   // [64][2048][1024] f32
    const f16*   __restrict__ Bg,    // [128][512][8] f16
    const float* __restrict__ dp,    // [64][512]
    const float* __restrict__ vvg,   // [512]
    float*       __restrict__ scores)// [64][2048]
{
  __shared__ __align__(16) f16 At[2][2048];    // [kgrp4][row64][8]
  __shared__ __align__(16) f16 Bt[2][16384];   // [kgrp4][col512][8]
  __shared__ float s_sc[64];

  const int tid  = threadIdx.x;
  const int lane = tid & 63;
  const int wave = tid >> 6;
  const int b    = blockIdx.x >> 5;
  const int s0   = (blockIdx.x & 31) << 6;

  if (tid < 64) s_sc[tid] = 0.0f;

  // A staging map: 8 threads per row, each converts 4 f32 -> 4 f16
  const int arow = tid >> 3;
  const int akq  = tid & 7;
  const float* aG = enc + ((size_t)(b*S_ + s0 + arow) << 10) + (akq << 2);
  const int aDst = ((akq>>1)<<9) + (arow<<3) + ((akq&1)<<2);

  // fragment read offsets (in halves)
  const int r16 = lane & 15, g = lane >> 4;
  const int aFrag = (g<<9)  + (r16<<3);
  const int colb  = wave << 6;
  const int bFrag = (g<<12) + ((colb + r16)<<3);

  f32x4 acc[4][4] = {};

  auto stage = [&](int buf, int t){
    // B: async global->LDS, linear copy, 4 x 16B per thread
    const f16* src = Bg + ((size_t)t << 14);
    #pragma unroll
    for (int i = 0; i < 4; ++i){
      int slot = (i<<9) + tid;
      __builtin_amdgcn_global_load_lds(
          (const __attribute__((address_space(1))) void*)(src + (slot<<3)),
          (__attribute__((address_space(3))) void*)(&Bt[buf][slot<<3]),
          16, 0, 0);
    }
    // A: f32 load (streaming) -> f16 -> LDS
    f32x4 a4 = __builtin_nontemporal_load((const f32x4*)(aG + (t<<5)));
    f16x4 h4; h4[0]=(f16)a4[0]; h4[1]=(f16)a4[1]; h4[2]=(f16)a4[2]; h4[3]=(f16)a4[3];
    *(f16x4*)&At[buf][aDst] = h4;
  };

  stage(0, 0);
  __syncthreads();

  for (int t = 0; t < 32; ++t){
    const int cur = t & 1;
    if (t < 31) stage(cur^1, t+1);
    f16x8 bfr[4];
    #pragma unroll
    for (int n = 0; n < 4; ++n) bfr[n] = *(const f16x8*)&Bt[cur][bFrag + (n<<7)];
    #pragma unroll
    for (int m = 0; m < 4; ++m){
      f16x8 af = *(const f16x8*)&At[cur][aFrag + (m<<7)];
      #pragma unroll
      for (int n = 0; n < 4; ++n)
        acc[m][n] = __builtin_amdgcn_mfma_f32_16x16x32_f16(af, bfr[n], acc[m][n], 0, 0, 0);
    }
    __syncthreads();
  }

  // epilogue: e = tanh(acc + dp[col]); score_row += v[col]*e
  float dpv[4], vvv[4];
  #pragma unroll
  for (int n = 0; n < 4; ++n){
    int c = colb + (n<<4) + r16;
    dpv[n] = dp[(b<<9) + c];
    vvv[n] = vvg[c];
  }
  float sp[4][4] = {};
  #pragma unroll
  for (int m = 0; m < 4; ++m)
    #pragma unroll
    for (int n = 0; n < 4; ++n)
      #pragma unroll
      for (int r = 0; r < 4; ++r){
        float e = fast_tanh(acc[m][n][r] + dpv[n]);
        sp[m][r] += vvv[n]*e;
      }
  // reduce across the 16 lanes sharing g (cols), then combine waves via LDS
  #pragma unroll
  for (int m = 0; m < 4; ++m)
    #pragma unroll
    for (int r = 0; r < 4; ++r){
      float x = sp[m][r];
      x += __shfl_xor(x, 1);
      x += __shfl_xor(x, 2);
      x += __shfl_xor(x, 4);
      x += __shfl_xor(x, 8);
      if (r16 == 0) atomicAdd(&s_sc[(m<<4) + (g<<2) + r], x);
    }
  __syncthreads();
  if (tid < 64) scores[((size_t)b << 11) + s0 + tid] = s_sc[tid];
}

// ---- k2: masked softmax over S per batch row ----
__global__ __launch_bounds__(256) void softmax_k(const float* __restrict__ sc,
                                                 const int* __restrict__ mask,
                                                 float* __restrict__ attn){
  const int b = blockIdx.x, tid = threadIdx.x;
  const int lane = tid & 63, wv = tid >> 6;
  __shared__ float rmx[4], rsm[4];
  float vals[8];
  float mx = -3.0e38f;
  #pragma unroll
  for (int i = 0; i < 8; ++i){
    int s = tid + (i<<8);
    float x = sc[(b<<11) + s];
    if (mask[(b<<11) + s] == 0) x = -1e10f;
    vals[i] = x; mx = fmaxf(mx, x);
  }
  #pragma unroll
  for (int o = 32; o >= 1; o >>= 1) mx = fmaxf(mx, __shfl_xor(mx, o));
  if (lane == 0) rmx[wv] = mx;
  __syncthreads();
  mx = fmaxf(fmaxf(rmx[0],rmx[1]), fmaxf(rmx[2],rmx[3]));
  float sm = 0.f;
  #pragma unroll
  for (int i = 0; i < 8; ++i){ vals[i] = __expf(vals[i]-mx); sm += vals[i]; }
  #pragma unroll
  for (int o = 32; o >= 1; o >>= 1) sm += __shfl_xor(sm, o);
  if (lane == 0) rsm[wv] = sm;
  __syncthreads();
  sm = rsm[0]+rsm[1]+rsm[2]+rsm[3];
  float inv = 1.0f / sm;
  #pragma unroll
  for (int i = 0; i < 8; ++i) attn[(b<<11) + tid + (i<<8)] = vals[i]*inv;
}

// ---- k3: context partials: part[b][ch][1024] = sum_{s in ch} attn*enc ----
__global__ __launch_bounds__(256) void ctx_partial_k(const float* __restrict__ enc,
                                                     const float* __restrict__ attn,
                                                     float* __restrict__ part){
  const int b = blockIdx.x >> 4, ch = blockIdx.x & 15;
  const int tid = threadIdx.x;
  const f32x4* e4 = (const f32x4*)(enc + ((size_t)(b*S_ + (ch<<7)) << 10)) + tid;
  const float* aw = attn + (b<<11) + (ch<<7);
  f32x4 acc = {0.f,0.f,0.f,0.f};
  #pragma unroll 4
  for (int s = 0; s < 128; ++s){
    float w = aw[s];
    f32x4 x = __builtin_nontemporal_load(e4 + s*256);
    acc += w * x;
  }
  ((f32x4*)part)[(blockIdx.x<<8) + tid] = acc;
}

// ---- k4: reduce 16 partials -> context ----
__global__ __launch_bounds__(256) void ctx_reduce_k(const float* __restrict__ part,
                                                    float* __restrict__ ctx){
  const int b = blockIdx.x, tid = threadIdx.x;
  f32x4 acc = {0.f,0.f,0.f,0.f};
  #pragma unroll
  for (int c = 0; c < 16; ++c)
    acc += ((const f32x4*)part)[(((b<<4)+c)<<8) + tid];
  ((f32x4*)ctx)[(b<<8) + tid] = acc;
}

extern "C" void kernel_launch(void* const* d_in, const int* in_sizes, int n_in,
                              void* d_out, int out_size, void* d_ws, size_t ws_size,
                              hipStream_t stream){
  (void)in_sizes; (void)n_in; (void)out_size;
  // workspace layout (total 5.625 MB): guard against undersized ws to avoid
  // OOB writes (clean absmax failure instead of a GPU fault).
  const size_t WS_NEED = (1u<<20) + B_*H_*4 + B_*S_*4 + (4u<<20);
  if (ws_size < WS_NEED) return;

  const float* dec_h = (const float*)d_in[0];
  const float* enc   = (const float*)d_in[1];
  const int*   mask  = (const int*)d_in[2];
  const float* Wd    = (const float*)d_in[3];
  const float* We    = (const float*)d_in[4];
  const float* v     = (const float*)d_in[5];
  float* out  = (float*)d_out;
  float* ctx  = out;                       // [64][1024]
  float* attn = out + B_*2*H_;             // [64][2048]

  f16*   Bg     = (f16*)d_ws;                              // 1 MB
  float* dproj  = (float*)((char*)d_ws + (1<<20));         // 128 KB
  float* scores = dproj + B_*H_;                           // 512 KB
  float* part   = scores + B_*S_;                          // 4 MB

  convert_we_k <<<2048, 256, 0, stream>>>(We, Bg);
  decproj_k    <<<256, 128, 0, stream>>>(dec_h, Wd, dproj);
  scores_k     <<<2048, 512, 0, stream>>>(enc, Bg, dproj, v, scores);
  softmax_k    <<<B_, 256, 0, stream>>>(scores, mask, attn);
  ctx_partial_k<<<B_*16, 256, 0, stream>>>(enc, attn, part);
  ctx_reduce_k <<<B_, 256, 0, stream>>>(part, ctx);
}